// Round 3
// baseline (379.177 us; speedup 1.0000x reference)
//
#include <hip/hip_runtime.h>
#include <hip/hip_bf16.h>
#include <math.h>

#define LOG2E_F 1.4426950408889634f

static constexpr int BT = 64;
static constexpr int DK = 64;
static constexpr int DV = 64;
static constexpr float SCALE = 0.125f;
static constexpr int PAD = 72;   // ushort row stride: 144 B, 16B-aligned
static constexpr int CPB = 4;    // chunks per block (persistent blocks, reg prefetch)

typedef unsigned short ushort_t;
typedef __attribute__((ext_vector_type(8))) short short8;
typedef __attribute__((ext_vector_type(4))) float f32x4;
typedef __attribute__((ext_vector_type(4))) ushort_t ushort4v;

#define MFMA16(a, b, c) __builtin_amdgcn_mfma_f32_16x16x32_bf16((a), (b), (c), 0, 0, 0)

__device__ __forceinline__ int SWZ(int a, int b){ return a * PAD + (b ^ (((a >> 3) & 3) << 3)); }
__device__ __forceinline__ int ZSW(int r, int c){ return r * PAD + (c ^ (((r >> 2) & 3) << 3)); }
__device__ __forceinline__ int LIN(int r, int c){ return r * PAD + c; }

__device__ __forceinline__ float logsig_log2e(float x){
    float l = (x >= 0.f) ? (-log1pf(expf(-x))) : (x - log1pf(expf(x)));
    return l * LOG2E_F;
}
__device__ __forceinline__ ushort_t f2bf(float x){   // RNE f32 -> bf16 bits
    unsigned u = __builtin_bit_cast(unsigned, x);
    unsigned r = u + 0x7FFFu + ((u >> 16) & 1u);
    return (ushort_t)(r >> 16);
}
__device__ __forceinline__ float bf2f(ushort_t u){
    return __builtin_bit_cast(float, ((unsigned)u) << 16);
}
__device__ __forceinline__ void split_bf(float x, ushort_t& h, ushort_t& l){
    h = f2bf(x);
    l = f2bf(x - bf2f(h));
}

// ===================== Stage A: per-chunk local state (split-bf16 MFMA) ==========
// Persistent blocks: CPB chunks each, next chunk's k/v prefetched into regs
// while current chunk stages+computes. A layout [v][k] (coalesced float4 store).
__global__ __launch_bounds__(256, 4) void stageA_kernel(
    const float* __restrict__ kg, const float* __restrict__ vg,
    const float* __restrict__ ig, const float* __restrict__ fg,
    float* __restrict__ A_ws, float* __restrict__ nloc_ws,
    float* __restrict__ fl_ws, float* __restrict__ mloc_ws,
    int T, int NT)
{
    const int cg = blockIdx.x, s = blockIdx.y, tid = threadIdx.x;
    const int w = tid >> 6, lane = tid & 63, ln = lane & 15, quad = lane >> 4;
    const int q8 = quad * 8;
    const int ct0 = cg * CPB;

    __shared__ __align__(16) ushort_t kth[BT * PAD];
    __shared__ __align__(16) ushort_t ktl[BT * PAD];
    __shared__ __align__(16) ushort_t vth[BT * PAD];
    __shared__ __align__(16) ushort_t vtl[BT * PAD];
    __shared__ float gsc[BT];

    // prologue: chunk ct0 loads
    size_t rowbase = (size_t)s * T + (size_t)ct0 * BT;
    float4 kr[4], vr[4];
    #pragma unroll
    for (int i = 0; i < 4; ++i){
        int idx = i * 1024 + tid * 4;
        kr[i] = *(const float4*)(kg + rowbase * DK + idx);
        vr[i] = *(const float4*)(vg + rowbase * DV + idx);
    }
    float fv = 0.f, iv = 0.f;
    if (tid < 64){ fv = fg[rowbase + tid]; iv = ig[rowbase + tid]; }

    #pragma unroll
    for (int c = 0; c < CPB; ++c){
        const int ct = ct0 + c;
        const size_t rb = (size_t)s * T + (size_t)ct * BT;

        // gates (wave 0)
        if (tid < 64){
            float b = logsig_log2e(fv);
            #pragma unroll
            for (int off = 1; off < 64; off <<= 1){
                float y = __shfl_up(b, off);
                if (tid >= off) b += y;
            }
            float f_last = __shfl(b, 63);
            float a = iv * LOG2E_F - b;
            float p = a;
            #pragma unroll
            for (int off = 32; off > 0; off >>= 1) p = fmaxf(p, __shfl_xor(p, off));
            gsc[tid] = exp2f(a - p);
            if (tid == 0){ fl_ws[s * NT + ct] = f_last; mloc_ws[s * NT + ct] = f_last + p; }
        }
        // prefetch next chunk (independent of everything below)
        float4 krn[4], vrn[4];
        float fvn = 0.f, ivn = 0.f;
        if (c + 1 < CPB){
            const size_t rb2 = rb + BT;
            #pragma unroll
            for (int i = 0; i < 4; ++i){
                int idx = i * 1024 + tid * 4;
                krn[i] = *(const float4*)(kg + rb2 * DK + idx);
                vrn[i] = *(const float4*)(vg + rb2 * DV + idx);
            }
            if (tid < 64){ fvn = fg[rb2 + tid]; ivn = ig[rb2 + tid]; }
        }
        __syncthreads();   // gsc visible; prev chunk's MFMA slab reads done

        // transpose-stage split-bf16 (k scaled by gsc[row])
        #pragma unroll
        for (int i = 0; i < 4; ++i){
            int idx = i * 1024 + tid * 4;
            int r = idx >> 6, c0 = idx & 63;
            float g = gsc[r];
            float kv[4] = {kr[i].x * g, kr[i].y * g, kr[i].z * g, kr[i].w * g};
            float vv[4] = {vr[i].x, vr[i].y, vr[i].z, vr[i].w};
            #pragma unroll
            for (int j = 0; j < 4; ++j){
                ushort_t h, l;
                split_bf(kv[j], h, l); kth[SWZ(c0 + j, r)] = h; ktl[SWZ(c0 + j, r)] = l;
                split_bf(vv[j], h, l); vth[SWZ(c0 + j, r)] = h; vtl[SWZ(c0 + j, r)] = l;
            }
        }
        __syncthreads();

        const int m = 16 * w + ln;
        short8 ah0 = *(const short8*)&kth[SWZ(m, q8)];
        short8 ah1 = *(const short8*)&kth[SWZ(m, 32 + q8)];
        short8 al0 = *(const short8*)&ktl[SWZ(m, q8)];
        short8 al1 = *(const short8*)&ktl[SWZ(m, 32 + q8)];
        float* Ab = A_ws + (size_t)(s * NT + ct) * 4096;
        #pragma unroll
        for (int t = 0; t < 4; ++t){
            f32x4 acc = {0.f, 0.f, 0.f, 0.f};
            short8 bh0 = *(const short8*)&vth[SWZ(16 * t + ln, q8)];
            short8 bh1 = *(const short8*)&vth[SWZ(16 * t + ln, 32 + q8)];
            short8 bl0 = *(const short8*)&vtl[SWZ(16 * t + ln, q8)];
            short8 bl1 = *(const short8*)&vtl[SWZ(16 * t + ln, 32 + q8)];
            acc = MFMA16(ah0, bh0, acc);
            acc = MFMA16(ah1, bh1, acc);
            acc = MFMA16(ah0, bl0, acc);
            acc = MFMA16(ah1, bl1, acc);
            acc = MFMA16(al0, bh0, acc);
            acc = MFMA16(al1, bh1, acc);
            *(f32x4*)(Ab + ((16 * t + ln) << 6) + 16 * w + quad * 4) = acc;
        }
        // nloc = colsum(kdec) via MFMA against all-ones
        {
            short8 ones;
            #pragma unroll
            for (int j = 0; j < 8; ++j) ones[j] = (short)0x3F80;
            f32x4 nacc = {0.f, 0.f, 0.f, 0.f};
            nacc = MFMA16(ah0, ones, nacc);
            nacc = MFMA16(ah1, ones, nacc);
            nacc = MFMA16(al0, ones, nacc);
            nacc = MFMA16(al1, ones, nacc);
            if (ln == 0){
                #pragma unroll
                for (int reg = 0; reg < 4; ++reg)
                    nloc_ws[((size_t)(s * NT + ct)) * DK + 16 * w + quad * 4 + reg] = nacc[reg];
            }
        }
        if (c + 1 < CPB){
            #pragma unroll
            for (int i = 0; i < 4; ++i){ kr[i] = krn[i]; vr[i] = vrn[i]; }
            fv = fvn; iv = ivn;
        }
    }
}

// ===================== Stage B: sequential combine (fp32) =====================
__global__ __launch_bounds__(256) void stageB_kernel(
    const float* __restrict__ A_ws, const float* __restrict__ nloc_ws,
    const float* __restrict__ fl_ws, const float* __restrict__ mloc_ws,
    float* __restrict__ Cws, float* __restrict__ nws, float* __restrict__ mws,
    int NT)
{
    const int vb = blockIdx.x, s = blockIdx.y, tid = threadIdx.x;
    __shared__ float decs[64], scs[64];

    if (tid < 64){
        float fl = fl_ws[s * NT + tid];
        float ml = mloc_ws[s * NT + tid];
        float F = fl, G = ml;
        #pragma unroll
        for (int off = 1; off < 64; off <<= 1){
            float Fp = __shfl_up(F, off);
            float Gp = __shfl_up(G, off);
            if (tid >= off){ G = fmaxf(Gp + F, G); F = Fp + F; }
        }
        float m_next = fmaxf(F, G);
        float m_cur  = __shfl_up(m_next, 1);
        if (tid == 0) m_cur = 0.f;
        decs[tid] = exp2f(fl + m_cur - m_next);
        scs[tid]  = exp2f(ml - m_next);
        if (vb == 0) mws[s * NT + tid] = m_cur;
    }
    __syncthreads();

    const size_t base = (size_t)s * NT * 4096 + (size_t)vb * 256 + tid;
    const float* Ab = A_ws + base;
    float*       Cb = Cws  + base;
    const bool do_n = (vb == 0) && (tid < 64);

    float C = 0.f, nreg = 0.f;
    float p[8], nl[8];
    #pragma unroll
    for (int i = 0; i < 8; ++i){ p[i] = Ab[(size_t)i * 4096]; nl[i] = 0.f; }
    if (do_n){
        #pragma unroll
        for (int i = 0; i < 8; ++i) nl[i] = nloc_ws[((size_t)(s * NT + i)) * DK + tid];
    }

    for (int t0 = 0; t0 < NT; t0 += 8){
        float qv[8], nq[8];
        const int tn = t0 + 8;
        #pragma unroll
        for (int i = 0; i < 8; ++i)
            qv[i] = (tn + i < NT) ? Ab[(size_t)(tn + i) * 4096] : 0.f;
        #pragma unroll
        for (int i = 0; i < 8; ++i) nq[i] = 0.f;
        if (do_n){
            #pragma unroll
            for (int i = 0; i < 8; ++i)
                if (tn + i < NT) nq[i] = nloc_ws[((size_t)(s * NT + tn + i)) * DK + tid];
        }
        #pragma unroll
        for (int i = 0; i < 8; ++i){
            const int t = t0 + i;
            Cb[(size_t)t * 4096] = C;
            if (do_n) nws[((size_t)(s * NT + t)) * DK + tid] = nreg;
            const float d = decs[t], sc = scs[t];
            C = C * d + p[i] * sc;
            if (do_n) nreg = nreg * d + nl[i] * sc;
        }
        #pragma unroll
        for (int i = 0; i < 8; ++i){ p[i] = qv[i]; nl[i] = nq[i]; }
    }
}

// ===================== Pass 2: per-chunk outputs (split-bf16 MFMA) ==============
// Persistent blocks: CPB chunks each; next chunk's k/C/q/v prefetched into regs
// staggered across phases so latency hides under compute. 4 barriers/chunk.
__global__ __launch_bounds__(256, 4) void pass2_kernel(
    const float* __restrict__ qg, const float* __restrict__ kg, const float* __restrict__ vg,
    const float* __restrict__ ig, const float* __restrict__ fg,
    const float* __restrict__ Cws, const float* __restrict__ nws, const float* __restrict__ mws,
    float* __restrict__ out, int T, int NT)
{
    const int cg = blockIdx.x, s = blockIdx.y, tid = threadIdx.x;
    const int w = tid >> 6, lane = tid & 63, ln = lane & 15, quad = lane >> 4;
    const int q8 = quad * 8;
    const int ct0 = cg * CPB;

    __shared__ __align__(16) ushort_t bufA[BT * PAD];  // k_hi (SWZ) -> C_hi [v][k] (SWZ)
    __shared__ __align__(16) ushort_t bufB[BT * PAD];  // k_lo (SWZ) -> C_lo (SWZ)
    __shared__ __align__(16) ushort_t bufZ[BT * PAD];  // Z [row][col] (ZSW)
    __shared__ __align__(16) ushort_t bufV[BT * PAD];  // v^T hi (SWZ)
    __shared__ float colterm[BT], Mr[BT], rowfac[BT], dncl[BT];
    __shared__ float nsh[DK], qn[BT], rowsum[BT];

    // ---- prologue: chunk ct0 loads ----
    {
        // nothing; loads below
    }
    size_t rb0 = (size_t)s * T + (size_t)ct0 * BT;
    float4 kr4[4], vr[4], Cr[4], qf[4];
    #pragma unroll
    for (int i = 0; i < 4; ++i){
        int idx = i * 1024 + tid * 4;
        kr4[i] = *(const float4*)(kg + rb0 * DK + idx);
        vr[i]  = *(const float4*)(vg + rb0 * DV + idx);
        Cr[i]  = *(const float4*)(Cws + ((size_t)(s * NT + ct0)) * 4096 + i * 1024 + tid * 4);
    }
    {
        const float* qrow = qg + (rb0 + 16 * w + ln) * DK;
        qf[0] = *(const float4*)(qrow + q8);
        qf[1] = *(const float4*)(qrow + q8 + 4);
        qf[2] = *(const float4*)(qrow + 32 + q8);
        qf[3] = *(const float4*)(qrow + 32 + q8 + 4);
    }
    float fv = 0.f, iv = 0.f, nv = 0.f, mv = 0.f;
    if (tid < 64){
        fv = fg[rb0 + tid];
        iv = ig[rb0 + tid];
        nv = nws[((size_t)(s * NT + ct0)) * DK + tid];
        mv = mws[s * NT + ct0];
    }

    #pragma unroll
    for (int c = 0; c < CPB; ++c){
        const int ct = ct0 + c;
        const size_t rowbase = (size_t)s * T + (size_t)ct * BT;

        // ---- P0: gates + stage k ----
        if (tid < 64){
            float b = logsig_log2e(fv);
            #pragma unroll
            for (int off = 1; off < 64; off <<= 1){
                float y = __shfl_up(b, off);
                if (tid >= off) b += y;
            }
            float a = iv * LOG2E_F - b;
            float p = a;
            #pragma unroll
            for (int off = 1; off < 64; off <<= 1){
                float y = __shfl_up(p, off);
                if (tid >= off) p = fmaxf(p, y);
            }
            float M = fmaxf(mv, p);
            colterm[tid] = a;
            Mr[tid] = M;
            rowfac[tid] = SCALE * exp2f(mv - M);
            dncl[tid] = exp2f(-(b + M));
            nsh[tid] = nv;
        }
        #pragma unroll
        for (int i = 0; i < 4; ++i){
            int idx = i * 1024 + tid * 4;
            int r = idx >> 6, c0 = idx & 63;
            float kv[4] = {kr4[i].x, kr4[i].y, kr4[i].z, kr4[i].w};
            ushort4v kh4, kl4;
            #pragma unroll
            for (int j = 0; j < 4; ++j){
                ushort_t h, l;
                split_bf(kv[j], h, l); kh4[j] = h; kl4[j] = l;
            }
            *(ushort4v*)&bufA[SWZ(r, c0)] = kh4;
            *(ushort4v*)&bufB[SWZ(r, c0)] = kl4;
        }
        // prefetch next chunk's k + gate scalars (kr4 dead now)
        float4 krn[4];
        float fvn = 0.f, ivn = 0.f, nvn = 0.f, mvn = 0.f;
        if (c + 1 < CPB){
            const size_t rb2 = rowbase + BT;
            #pragma unroll
            for (int i = 0; i < 4; ++i)
                krn[i] = *(const float4*)(kg + rb2 * DK + i * 1024 + tid * 4);
            if (tid < 64){
                fvn = fg[rb2 + tid];
                ivn = ig[rb2 + tid];
                nvn = nws[((size_t)(s * NT + ct + 1)) * DK + tid];
                mvn = mws[s * NT + ct + 1];
            }
        }
        __syncthreads();   // #1: k staged; gates visible

        // ---- P1: q frags, qn, v-stage, S-MFMA, Z ----
        const int mrow = 16 * w + ln;
        float a0[8] = {qf[0].x, qf[0].y, qf[0].z, qf[0].w, qf[1].x, qf[1].y, qf[1].z, qf[1].w};
        float a1[8] = {qf[2].x, qf[2].y, qf[2].z, qf[2].w, qf[3].x, qf[3].y, qf[3].z, qf[3].w};
        short8 ah0, al0, ah1, al1;
        #pragma unroll
        for (int j = 0; j < 8; ++j){
            ushort_t h, l;
            split_bf(a0[j], h, l); ah0[j] = (short)h; al0[j] = (short)l;
            split_bf(a1[j], h, l); ah1[j] = (short)h; al1[j] = (short)l;
        }
        {
            float p = 0.f;
            #pragma unroll
            for (int j = 0; j < 8; ++j){
                p = fmaf(a0[j], nsh[q8 + j], p);
                p = fmaf(a1[j], nsh[32 + q8 + j], p);
            }
            p += __shfl_xor(p, 16);
            p += __shfl_xor(p, 32);
            if (quad == 0) qn[mrow] = p;
        }
        #pragma unroll
        for (int i = 0; i < 4; ++i){
            int idx = i * 1024 + tid * 4;
            int r = idx >> 6, c0 = idx & 63;
            float vv[4] = {vr[i].x, vr[i].y, vr[i].z, vr[i].w};
            #pragma unroll
            for (int j = 0; j < 4; ++j) bufV[SWZ(c0 + j, r)] = f2bf(vv[j]);
        }
        f32x4 sacc[4];
        #pragma unroll
        for (int t = 0; t < 4; ++t){
            sacc[t] = (f32x4){0.f, 0.f, 0.f, 0.f};
            short8 bh0 = *(const short8*)&bufA[SWZ(16 * t + ln, q8)];
            short8 bh1 = *(const short8*)&bufA[SWZ(16 * t + ln, 32 + q8)];
            short8 bl0 = *(const short8*)&bufB[SWZ(16 * t + ln, q8)];
            short8 bl1 = *(const short8*)&bufB[SWZ(16 * t + ln, 32 + q8)];
            sacc[t] = MFMA16(ah0, bh0, sacc[t]);
            sacc[t] = MFMA16(ah1, bh1, sacc[t]);
            sacc[t] = MFMA16(ah0, bl0, sacc[t]);
            sacc[t] = MFMA16(ah1, bl1, sacc[t]);
            sacc[t] = MFMA16(al0, bh0, sacc[t]);
            sacc[t] = MFMA16(al1, bh1, sacc[t]);
        }
        {
            float rsum[4] = {0.f, 0.f, 0.f, 0.f};
            float Mrv[4];
            #pragma unroll
            for (int reg = 0; reg < 4; ++reg) Mrv[reg] = Mr[16 * w + quad * 4 + reg];
            #pragma unroll
            for (int t = 0; t < 4; ++t){
                int cc = 16 * t + ln;
                float cterm = colterm[cc];
                #pragma unroll
                for (int reg = 0; reg < 4; ++reg){
                    int r = 16 * w + quad * 4 + reg;
                    float vS = (cc <= r) ? sacc[t][reg] * SCALE * exp2f(cterm - Mrv[reg]) : 0.f;
                    bufZ[ZSW(r, cc)] = f2bf(vS);
                    rsum[reg] += vS;
                }
            }
            #pragma unroll
            for (int off = 1; off < 16; off <<= 1){
                #pragma unroll
                for (int reg = 0; reg < 4; ++reg) rsum[reg] += __shfl_xor(rsum[reg], off);
            }
            if (ln == 0){
                #pragma unroll
                for (int reg = 0; reg < 4; ++reg) rowsum[16 * w + quad * 4 + reg] = rsum[reg];
            }
        }
        __syncthreads();   // #2: k reads done; v^T + Z staged

        // ---- P2: stage C (from Cr) + prefetch next C/q/v ----
        #pragma unroll
        for (int i = 0; i < 4; ++i){
            int idx = i * 1024 + tid * 4;
            int vrow = idx >> 6, k0 = idx & 63;
            float cv[4] = {Cr[i].x, Cr[i].y, Cr[i].z, Cr[i].w};
            ushort4v ch4, cl4;
            #pragma unroll
            for (int j = 0; j < 4; ++j){
                ushort_t h, l;
                split_bf(cv[j], h, l); ch4[j] = h; cl4[j] = l;
            }
            *(ushort4v*)&bufA[SWZ(vrow, k0)] = ch4;
            *(ushort4v*)&bufB[SWZ(vrow, k0)] = cl4;
        }
        float4 Crn[4], qfn[4], vrn[4];
        if (c + 1 < CPB){
            const size_t rb2 = rowbase + BT;
            #pragma unroll
            for (int i = 0; i < 4; ++i){
                Crn[i] = *(const float4*)(Cws + ((size_t)(s * NT + ct + 1)) * 4096 + i * 1024 + tid * 4);
                vrn[i] = *(const float4*)(vg + rb2 * DV + i * 1024 + tid * 4);
            }
            const float* qrow2 = qg + (rb2 + 16 * w + ln) * DK;
            qfn[0] = *(const float4*)(qrow2 + q8);
            qfn[1] = *(const float4*)(qrow2 + q8 + 4);
            qfn[2] = *(const float4*)(qrow2 + 32 + q8);
            qfn[3] = *(const float4*)(qrow2 + 32 + q8 + 4);
        }
        __syncthreads();   // #3: C staged

        // ---- P3: qC MFMA, Sv MFMA, epilogue ----
        f32x4 acc[4];
        #pragma unroll
        for (int t = 0; t < 4; ++t){
            acc[t] = (f32x4){0.f, 0.f, 0.f, 0.f};
            short8 bh0 = *(const short8*)&bufA[SWZ(16 * t + ln, q8)];
            short8 bh1 = *(const short8*)&bufA[SWZ(16 * t + ln, 32 + q8)];
            short8 bl0 = *(const short8*)&bufB[SWZ(16 * t + ln, q8)];
            short8 bl1 = *(const short8*)&bufB[SWZ(16 * t + ln, 32 + q8)];
            acc[t] = MFMA16(ah0, bh0, acc[t]);
            acc[t] = MFMA16(ah1, bh1, acc[t]);
            acc[t] = MFMA16(ah0, bl0, acc[t]);
            acc[t] = MFMA16(ah1, bl1, acc[t]);
            acc[t] = MFMA16(al0, bh0, acc[t]);
            acc[t] = MFMA16(al1, bh1, acc[t]);
        }
        float rf[4], inv[4];
        #pragma unroll
        for (int reg = 0; reg < 4; ++reg){
            int r = 16 * w + quad * 4 + reg;
            rf[reg] = rowfac[r];
            float dn = fabsf(rf[reg] * qn[r] + rowsum[r]);
            inv[reg] = 1.f / fmaxf(dn, dncl[r]);
        }
        #pragma unroll
        for (int t = 0; t < 4; ++t){
            #pragma unroll
            for (int reg = 0; reg < 4; ++reg) acc[t][reg] *= rf[reg];
        }
        short8 az0 = *(const short8*)&bufZ[ZSW(mrow, q8)];
        short8 az1 = *(const short8*)&bufZ[ZSW(mrow, 32 + q8)];
        #pragma unroll
        for (int t = 0; t < 4; ++t){
            short8 bh0 = *(const short8*)&bufV[SWZ(16 * t + ln, q8)];
            short8 bh1 = *(const short8*)&bufV[SWZ(16 * t + ln, 32 + q8)];
            acc[t] = MFMA16(az0, bh0, acc[t]);
            acc[t] = MFMA16(az1, bh1, acc[t]);
        }
        #pragma unroll
        for (int t = 0; t < 4; ++t){
            int cc = 16 * t + ln;
            #pragma unroll
            for (int reg = 0; reg < 4; ++reg){
                int r = 16 * w + quad * 4 + reg;
                out[(rowbase + r) * DV + cc] = acc[t][reg] * inv[reg];
            }
        }

        if (c + 1 < CPB){
            __syncthreads();   // #4: slab + scalar reuse barrier
            #pragma unroll
            for (int i = 0; i < 4; ++i){
                kr4[i] = krn[i]; Cr[i] = Crn[i]; qf[i] = qfn[i]; vr[i] = vrn[i];
            }
            fv = fvn; iv = ivn; nv = nvn; mv = mvn;
        }
    }
}

// ---------------- Fallback: fused sequential fp32 (no workspace) ----------------
__global__ __launch_bounds__(256) void fused_kernel(
    const float* __restrict__ qg, const float* __restrict__ kg, const float* __restrict__ vg,
    const float* __restrict__ ig, const float* __restrict__ fg,
    float* __restrict__ out, int T, int NT)
{
    const int s = blockIdx.x;
    const int tid = threadIdx.x;
    const int lane = tid & 63;

    __shared__ float X[BT][DK + 1];
    __shared__ float Y[BT][DK + 1];
    __shared__ float Cb[DK][DV];
    __shared__ __hip_bfloat16 Zh[BT][BT];
    __shared__ float colterm[BT], Mr[BT], rowfac[BT], dncl[BT], gscale[BT];
    __shared__ float nsh[DK], qn[BT], rowsum[BT], denom[BT];
    __shared__ float sh_dec;

    const float* qseq = qg + (size_t)s * T * DK;
    const float* kseq = kg + (size_t)s * T * DK;
    const float* vseq = vg + (size_t)s * T * DV;
    const float* iseq = ig + (size_t)s * T;
    const float* fseq = fg + (size_t)s * T;

    for (int idx = tid; idx < DK * DV; idx += 256) Cb[idx >> 6][idx & 63] = 0.f;
    if (tid < 64) nsh[lane] = 0.f;
    float m = 0.f;
    __syncthreads();

    const int r0 = (tid >> 4) * 4;
    const int c0 = (tid & 15) * 4;
    const int v0 = c0;

    for (int t = 0; t < NT; ++t){
        const size_t rb = (size_t)t * BT;
        if (tid < 64){
            float b = logsig_log2e(fseq[rb + lane]);
            #pragma unroll
            for (int off = 1; off < 64; off <<= 1){
                float y = __shfl_up(b, off);
                if (lane >= off) b += y;
            }
            float f_last = __shfl(b, 63);
            float a = iseq[rb + lane] * LOG2E_F - b;
            float p = a;
            #pragma unroll
            for (int off = 1; off < 64; off <<= 1){
                float y = __shfl_up(p, off);
                if (lane >= off) p = fmaxf(p, y);
            }
            float M = fmaxf(m, p);
            colterm[lane] = a;
            Mr[lane] = M;
            rowfac[lane] = SCALE * exp2f(m - M);
            dncl[lane] = exp2f(-(b + M));
            float g = a + f_last;
            float gm = g;
            #pragma unroll
            for (int off = 32; off > 0; off >>= 1) gm = fmaxf(gm, __shfl_xor(gm, off));
            float m_next = fmaxf(f_last + m, gm);
            gscale[lane] = exp2f(g - m_next);
            if (tid == 0) sh_dec = exp2f(f_last + m - m_next);
            m = m_next;
        }
        #pragma unroll
        for (int base = 0; base < BT * DK; base += 1024){
            int idx = base + tid * 4;
            int r = idx >> 6, c = idx & 63;
            float4 a4 = *(const float4*)(qseq + rb * DK + idx);
            X[r][c] = a4.x; X[r][c+1] = a4.y; X[r][c+2] = a4.z; X[r][c+3] = a4.w;
            float4 b4 = *(const float4*)(kseq + rb * DK + idx);
            Y[r][c] = b4.x; Y[r][c+1] = b4.y; Y[r][c+2] = b4.z; Y[r][c+3] = b4.w;
        }
        __syncthreads();

        float sacc[4][4] = {};
        for (int x = 0; x < DK; ++x){
            float xr[4], yc[4];
            #pragma unroll
            for (int j = 0; j < 4; ++j) xr[j] = X[r0 + j][x];
            #pragma unroll
            for (int j = 0; j < 4; ++j) yc[j] = Y[c0 + j][x];
            #pragma unroll
            for (int j = 0; j < 4; ++j)
                #pragma unroll
                for (int jj = 0; jj < 4; ++jj)
                    sacc[j][jj] = fmaf(xr[j], yc[jj], sacc[j][jj]);
        }
        float rs[4];
        #pragma unroll
        for (int j = 0; j < 4; ++j){
            int r = r0 + j;
            float Mrv = Mr[r];
            float acc = 0.f;
            #pragma unroll
            for (int jj = 0; jj < 4; ++jj){
                int c = c0 + jj;
                float vS = (c <= r) ? sacc[j][jj] * SCALE * exp2f(colterm[c] - Mrv) : 0.f;
                Zh[r][c] = __float2bfloat16(vS);
                acc += vS;
            }
            rs[j] = acc;
        }
        #pragma unroll
        for (int off = 1; off < 16; off <<= 1){
            #pragma unroll
            for (int j = 0; j < 4; ++j) rs[j] += __shfl_xor(rs[j], off);
        }
        if ((tid & 15) == 0){
            #pragma unroll
            for (int j = 0; j < 4; ++j) rowsum[r0 + j] = rs[j];
        }
        float acc1[4][4] = {};
        for (int x = 0; x < DK; ++x){
            float xr[4], yv[4];
            #pragma unroll
            for (int j = 0; j < 4; ++j) xr[j] = X[r0 + j][x];
            #pragma unroll
            for (int j = 0; j < 4; ++j) yv[j] = Cb[x][v0 + j];
            #pragma unroll
            for (int j = 0; j < 4; ++j)
                #pragma unroll
                for (int jj = 0; jj < 4; ++jj)
                    acc1[j][jj] = fmaf(xr[j], yv[jj], acc1[j][jj]);
        }
        if (tid < 64){
            float acc = 0.f;
            for (int x = 0; x < DK; ++x) acc = fmaf(X[lane][x], nsh[x], acc);
            qn[lane] = acc;
        }
        __syncthreads();

        #pragma unroll
        for (int base = 0; base < BT * DV; base += 1024){
            int idx = base + tid * 4;
            int r = idx >> 6, c = idx & 63;
            float4 a4 = *(const float4*)(vseq + rb * DV + idx);
            X[r][c] = a4.x; X[r][c+1] = a4.y; X[r][c+2] = a4.z; X[r][c+3] = a4.w;
        }
        if (tid < 64){
            float dn = fabsf(rowfac[lane] * qn[lane] + rowsum[lane]);
            denom[lane] = fmaxf(dn, dncl[lane]);
        }
        __syncthreads();

        float acc2[4][4] = {};
        for (int c = 0; c < BT; ++c){
            float zr[4], xv[4];
            #pragma unroll
            for (int j = 0; j < 4; ++j) zr[j] = __bfloat162float(Zh[r0 + j][c]);
            #pragma unroll
            for (int j = 0; j < 4; ++j) xv[j] = X[c][v0 + j];
            #pragma unroll
            for (int j = 0; j < 4; ++j)
                #pragma unroll
                for (int jj = 0; jj < 4; ++jj)
                    acc2[j][jj] = fmaf(zr[j], xv[jj], acc2[j][jj]);
        }
        #pragma unroll
        for (int j = 0; j < 4; ++j){
            int r = r0 + j;
            float rf = rowfac[r];
            float inv = 1.f / denom[r];
            float4 h4;
            h4.x = (acc1[j][0] * rf + acc2[j][0]) * inv;
            h4.y = (acc1[j][1] * rf + acc2[j][1]) * inv;
            h4.z = (acc1[j][2] * rf + acc2[j][2]) * inv;
            h4.w = (acc1[j][3] * rf + acc2[j][3]) * inv;
            *(float4*)(out + ((size_t)s * T + rb + r) * DV + v0) = h4;
        }
        {
            float dec = sh_dec;
            float cr[4][4];
            #pragma unroll
            for (int j = 0; j < 4; ++j)
                #pragma unroll
                for (int jj = 0; jj < 4; ++jj)
                    cr[j][jj] = Cb[r0 + j][c0 + jj] * dec;
            for (int c = 0; c < BT; ++c){
                float gs = gscale[c];
                float kd[4], xv[4];
                #pragma unroll
                for (int j = 0; j < 4; ++j) kd[j] = Y[c][r0 + j] * gs;
                #pragma unroll
                for (int jj = 0; jj < 4; ++jj) xv[jj] = X[c][c0 + jj];
                #pragma unroll
                for (int j = 0; j < 4; ++j)
                    #pragma unroll
                    for (int jj = 0; jj < 4; ++jj)
                        cr[j][jj] = fmaf(kd[j], xv[jj], cr[j][jj]);
            }
            #pragma unroll
            for (int j = 0; j < 4; ++j)
                #pragma unroll
                for (int jj = 0; jj < 4; ++jj)
                    Cb[r0 + j][c0 + jj] = cr[j][jj];
        }
        if (tid < 64){
            float acc = 0.f;
            for (int c = 0; c < BT; ++c) acc = fmaf(Y[c][lane], gscale[c], acc);
            nsh[lane] = nsh[lane] * sh_dec + acc;
        }
        __syncthreads();
    }
}

extern "C" void kernel_launch(void* const* d_in, const int* in_sizes, int n_in,
                              void* d_out, int out_size, void* d_ws, size_t ws_size,
                              hipStream_t stream)
{
    const float* q  = (const float*)d_in[0];
    const float* k  = (const float*)d_in[1];
    const float* v  = (const float*)d_in[2];
    const float* ii = (const float*)d_in[3];
    const float* ff = (const float*)d_in[4];
    float* out = (float*)d_out;

    const int T  = 4096;
    const int BH = in_sizes[3] / T;
    const int NT = T / BT;

    const size_t szC  = (size_t)BH * NT * DK * DV * sizeof(float);
    const size_t szA  = szC;
    const size_t szn  = (size_t)BH * NT * DK * sizeof(float);
    const size_t szs  = (size_t)BH * NT * sizeof(float);

    const size_t need_new = szA + szC + 2 * szn + 3 * szs;

    if (ws_size >= need_new && (NT % CPB) == 0){
        char* p = (char*)d_ws;
        float* A_ws    = (float*)p;            p += szA;
        float* Cws     = (float*)p;            p += szC;
        float* nloc_ws = (float*)p;            p += szn;
        float* nws     = (float*)p;            p += szn;
        float* fl_ws   = (float*)p;            p += szs;
        float* mloc_ws = (float*)p;            p += szs;
        float* mws     = (float*)p;
        stageA_kernel<<<dim3(NT / CPB, BH), 256, 0, stream>>>(k, v, ii, ff, A_ws, nloc_ws, fl_ws, mloc_ws, T, NT);
        stageB_kernel<<<dim3(16, BH), 256, 0, stream>>>(A_ws, nloc_ws, fl_ws, mloc_ws, Cws, nws, mws, NT);
        pass2_kernel<<<dim3(NT / CPB, BH), 256, 0, stream>>>(q, k, v, ii, ff, Cws, nws, mws, out, T, NT);
    } else {
        fused_kernel<<<dim3(BH), 256, 0, stream>>>(q, k, v, ii, ff, out, T, NT);
    }
}

// Round 4
// 369.058 us; speedup vs baseline: 1.0274x; 1.0274x over previous
//
#include <hip/hip_runtime.h>
#include <hip/hip_bf16.h>
#include <math.h>

#define LOG2E_F 1.4426950408889634f

static constexpr int BT = 64;
static constexpr int DK = 64;
static constexpr int DV = 64;
static constexpr float SCALE = 0.125f;
static constexpr int PAD = 72;   // ushort row stride: 144 B, 16B-aligned
static constexpr int CPB = 4;    // chunks per pass2 block (group size)

typedef unsigned short ushort_t;
typedef __attribute__((ext_vector_type(8))) short short8;
typedef __attribute__((ext_vector_type(4))) float f32x4;
typedef __attribute__((ext_vector_type(4))) ushort_t ushort4v;

#define MFMA16(a, b, c) __builtin_amdgcn_mfma_f32_16x16x32_bf16((a), (b), (c), 0, 0, 0)

__device__ __forceinline__ int SWZ(int a, int b){ return a * PAD + (b ^ (((a >> 3) & 3) << 3)); }
__device__ __forceinline__ int ZSW(int r, int c){ return r * PAD + (c ^ (((r >> 2) & 3) << 3)); }

__device__ __forceinline__ float logsig_log2e(float x){
    float l = (x >= 0.f) ? (-log1pf(expf(-x))) : (x - log1pf(expf(x)));
    return l * LOG2E_F;
}
__device__ __forceinline__ ushort_t f2bf(float x){   // RNE f32 -> bf16 bits
    unsigned u = __builtin_bit_cast(unsigned, x);
    unsigned r = u + 0x7FFFu + ((u >> 16) & 1u);
    return (ushort_t)(r >> 16);
}
__device__ __forceinline__ float bf2f(ushort_t u){
    return __builtin_bit_cast(float, ((unsigned)u) << 16);
}
__device__ __forceinline__ void split_bf(float x, ushort_t& h, ushort_t& l){
    h = f2bf(x);
    l = f2bf(x - bf2f(h));
}

// ===================== Stage A: per-chunk local state (split-bf16 MFMA) ==========
// A workspace: per-chunk slab of 4096 floats, [vdim][kdim] (coalesced float4 store).
__global__ __launch_bounds__(256, 4) void stageA_kernel(
    const float* __restrict__ kg, const float* __restrict__ vg,
    const float* __restrict__ ig, const float* __restrict__ fg,
    float* __restrict__ A_ws, float* __restrict__ nloc_ws,
    float* __restrict__ fl_ws, float* __restrict__ mloc_ws,
    int T, int NT)
{
    const int ct = blockIdx.x, s = blockIdx.y, tid = threadIdx.x;
    const int w = tid >> 6, lane = tid & 63, ln = lane & 15, quad = lane >> 4;
    const int q8 = quad * 8;

    __shared__ __align__(16) ushort_t kth[BT * PAD];  // kdec^T hi  [kdim][row] swz
    __shared__ __align__(16) ushort_t ktl[BT * PAD];  // kdec^T lo
    __shared__ __align__(16) ushort_t vth[BT * PAD];  // v^T hi     [vdim][row] swz
    __shared__ __align__(16) ushort_t vtl[BT * PAD];  // v^T lo
    __shared__ float gsc[BT];

    const size_t rowbase = (size_t)s * T + (size_t)ct * BT;
    const float* kc = kg + rowbase * DK;
    const float* vc = vg + rowbase * DV;

    float4 kr[4], vr[4];
    #pragma unroll
    for (int i = 0; i < 4; ++i){
        int idx = i * 1024 + tid * 4;
        kr[i] = *(const float4*)(kc + idx);
        vr[i] = *(const float4*)(vc + idx);
    }
    if (tid < 64){
        float b = logsig_log2e(fg[rowbase + tid]);
        #pragma unroll
        for (int off = 1; off < 64; off <<= 1){
            float y = __shfl_up(b, off);
            if (tid >= off) b += y;
        }
        float f_last = __shfl(b, 63);
        float a = ig[rowbase + tid] * LOG2E_F - b;
        float p = a;
        #pragma unroll
        for (int off = 32; off > 0; off >>= 1) p = fmaxf(p, __shfl_xor(p, off));
        gsc[tid] = exp2f(a - p);
        if (tid == 0){ fl_ws[s * NT + ct] = f_last; mloc_ws[s * NT + ct] = f_last + p; }
    }
    __syncthreads();
    // transpose-stage split-bf16 (k scaled by gsc[row]); swizzled scatter (~2-way)
    #pragma unroll
    for (int i = 0; i < 4; ++i){
        int idx = i * 1024 + tid * 4;
        int r = idx >> 6, c0 = idx & 63;
        float g = gsc[r];
        float kv[4] = {kr[i].x * g, kr[i].y * g, kr[i].z * g, kr[i].w * g};
        float vv[4] = {vr[i].x, vr[i].y, vr[i].z, vr[i].w};
        #pragma unroll
        for (int j = 0; j < 4; ++j){
            ushort_t h, l;
            split_bf(kv[j], h, l); kth[SWZ(c0 + j, r)] = h; ktl[SWZ(c0 + j, r)] = l;
            split_bf(vv[j], h, l); vth[SWZ(c0 + j, r)] = h; vtl[SWZ(c0 + j, r)] = l;
        }
    }
    __syncthreads();

    const int m = 16 * w + ln;
    short8 ah0 = *(const short8*)&kth[SWZ(m, q8)];
    short8 ah1 = *(const short8*)&kth[SWZ(m, 32 + q8)];
    short8 al0 = *(const short8*)&ktl[SWZ(m, q8)];
    short8 al1 = *(const short8*)&ktl[SWZ(m, 32 + q8)];
    float* Ab = A_ws + (size_t)(s * NT + ct) * 4096;
    #pragma unroll
    for (int t = 0; t < 4; ++t){
        f32x4 acc = {0.f, 0.f, 0.f, 0.f};
        short8 bh0 = *(const short8*)&vth[SWZ(16 * t + ln, q8)];
        short8 bh1 = *(const short8*)&vth[SWZ(16 * t + ln, 32 + q8)];
        short8 bl0 = *(const short8*)&vtl[SWZ(16 * t + ln, q8)];
        short8 bl1 = *(const short8*)&vtl[SWZ(16 * t + ln, 32 + q8)];
        acc = MFMA16(ah0, bh0, acc);
        acc = MFMA16(ah1, bh1, acc);
        acc = MFMA16(ah0, bl0, acc);
        acc = MFMA16(ah1, bl1, acc);
        acc = MFMA16(al0, bh0, acc);
        acc = MFMA16(al1, bh1, acc);
        // acc[reg] = A[k = 16w+quad*4+reg][v = 16t+ln]; store [v][k] coalesced
        *(f32x4*)(Ab + ((16 * t + ln) << 6) + 16 * w + quad * 4) = acc;
    }
    // nloc = colsum(kdec) via MFMA against all-ones B fragment
    {
        short8 ones;
        #pragma unroll
        for (int j = 0; j < 8; ++j) ones[j] = (short)0x3F80;   // bf16 1.0
        f32x4 nacc = {0.f, 0.f, 0.f, 0.f};
        nacc = MFMA16(ah0, ones, nacc);
        nacc = MFMA16(ah1, ones, nacc);
        nacc = MFMA16(al0, ones, nacc);
        nacc = MFMA16(al1, ones, nacc);
        if (ln == 0){
            #pragma unroll
            for (int reg = 0; reg < 4; ++reg)
                nloc_ws[((size_t)(s * NT + ct)) * DK + 16 * w + quad * 4 + reg] = nacc[reg];
        }
    }
}

// ===================== Stage B: global scan, boundary states only ==============
// Scans all NT chunks but writes C/n states only at group boundaries (t%CPB==0),
// plus per-chunk scalars (m, dec, sc) for pass2's in-register within-group scan.
__global__ __launch_bounds__(256) void stageB_kernel(
    const float* __restrict__ A_ws, const float* __restrict__ nloc_ws,
    const float* __restrict__ fl_ws, const float* __restrict__ mloc_ws,
    float* __restrict__ Cb_ws, float* __restrict__ nb_ws,
    float* __restrict__ mws, float* __restrict__ decs_ws, float* __restrict__ scs_ws,
    int NT)
{
    const int vb = blockIdx.x, s = blockIdx.y, tid = threadIdx.x;
    const int NG = NT >> 2;
    __shared__ float decs[64], scs[64];

    if (tid < 64){
        float fl = fl_ws[s * NT + tid];
        float ml = mloc_ws[s * NT + tid];
        float F = fl, G = ml;
        #pragma unroll
        for (int off = 1; off < 64; off <<= 1){
            float Fp = __shfl_up(F, off);
            float Gp = __shfl_up(G, off);
            if (tid >= off){ G = fmaxf(Gp + F, G); F = Fp + F; }
        }
        float m_next = fmaxf(F, G);
        float m_cur  = __shfl_up(m_next, 1);
        if (tid == 0) m_cur = 0.f;
        float d  = exp2f(fl + m_cur - m_next);
        float sc = exp2f(ml - m_next);
        decs[tid] = d;
        scs[tid]  = sc;
        if (vb == 0){
            mws[s * NT + tid]     = m_cur;
            decs_ws[s * NT + tid] = d;
            scs_ws[s * NT + tid]  = sc;
        }
    }
    __syncthreads();

    const size_t base = (size_t)s * NT * 4096 + (size_t)vb * 256 + tid;
    const float* Ab = A_ws + base;
    const bool do_n = (vb == 0) && (tid < 64);

    float C = 0.f, nreg = 0.f;
    float p[8], nl[8];
    #pragma unroll
    for (int i = 0; i < 8; ++i){ p[i] = Ab[(size_t)i * 4096]; nl[i] = 0.f; }
    if (do_n){
        #pragma unroll
        for (int i = 0; i < 8; ++i) nl[i] = nloc_ws[((size_t)(s * NT + i)) * DK + tid];
    }

    for (int t0 = 0; t0 < NT; t0 += 8){
        float qv[8], nq[8];
        const int tn = t0 + 8;
        #pragma unroll
        for (int i = 0; i < 8; ++i)
            qv[i] = (tn + i < NT) ? Ab[(size_t)(tn + i) * 4096] : 0.f;
        #pragma unroll
        for (int i = 0; i < 8; ++i) nq[i] = 0.f;
        if (do_n){
            #pragma unroll
            for (int i = 0; i < 8; ++i)
                if (tn + i < NT) nq[i] = nloc_ws[((size_t)(s * NT + tn + i)) * DK + tid];
        }
        #pragma unroll
        for (int i = 0; i < 8; ++i){
            const int t = t0 + i;
            if ((t & 3) == 0){
                const int g = t >> 2;
                Cb_ws[((size_t)(s * NG + g)) * 4096 + (size_t)vb * 256 + tid] = C;
                if (do_n) nb_ws[((size_t)(s * NG + g)) * 64 + tid] = nreg;
            }
            const float d = decs[t], sc = scs[t];
            C = C * d + p[i] * sc;
            if (do_n) nreg = nreg * d + nl[i] * sc;
        }
        #pragma unroll
        for (int i = 0; i < 8; ++i){ p[i] = qv[i]; nl[i] = nq[i]; }
    }
}

// ===================== Pass 2: group of CPB chunks, C-scan in registers =========
// Persistent state per thread: C_run (16 f32, [v][k] ownership idx=i*1024+tid*4)
// + preloaded per-chunk scalars. NO multi-tile register prefetch (R3 lesson).
__global__ __launch_bounds__(256, 4) void pass2_kernel(
    const float* __restrict__ qg, const float* __restrict__ kg, const float* __restrict__ vg,
    const float* __restrict__ ig, const float* __restrict__ fg,
    const float* __restrict__ A_ws, const float* __restrict__ Cb_ws,
    const float* __restrict__ nb_ws, const float* __restrict__ nloc_ws,
    const float* __restrict__ mws, const float* __restrict__ decs_ws,
    const float* __restrict__ scs_ws,
    float* __restrict__ out, int T, int NT)
{
    const int g = blockIdx.x, s = blockIdx.y, tid = threadIdx.x;
    const int w = tid >> 6, lane = tid & 63, ln = lane & 15, quad = lane >> 4;
    const int q8 = quad * 8;
    const int ct0 = g * CPB;
    const int NG = NT >> 2;

    __shared__ __align__(16) ushort_t bufA[BT * PAD];  // k_hi (SWZ) -> C_hi [v][k] (SWZ)
    __shared__ __align__(16) ushort_t bufB[BT * PAD];  // k_lo (SWZ) -> C_lo (SWZ)
    __shared__ __align__(16) ushort_t bufZ[BT * PAD];  // Z [row][col] (ZSW)
    __shared__ __align__(16) ushort_t bufV[BT * PAD];  // v^T hi (SWZ)
    __shared__ float colterm[BT], Mr[BT], rowfac[BT], dncl[BT];
    __shared__ float nsh[DK], qn[BT], rowsum[BT];

    // ---- persistent state init ----
    f32x4 Crun[4];
    {
        const float* Cb = Cb_ws + ((size_t)(s * NG + g)) * 4096;
        #pragma unroll
        for (int i = 0; i < 4; ++i)
            Crun[i] = *(const f32x4*)(Cb + i * 1024 + tid * 4);
    }
    if (tid < 64) nsh[tid] = nb_ws[((size_t)(s * NG + g)) * 64 + tid];

    // per-chunk small preloads (static arrays, unrolled indexing only)
    float fvs[CPB], ivs[CPB], nlv[CPB], mvs[CPB], dcv[CPB], scv[CPB];
    #pragma unroll
    for (int c = 0; c < CPB; ++c){
        const int ct = ct0 + c;
        const size_t rb = (size_t)s * T + (size_t)ct * BT;
        fvs[c] = 0.f; ivs[c] = 0.f; nlv[c] = 0.f;
        if (tid < 64){
            fvs[c] = fg[rb + tid];
            ivs[c] = ig[rb + tid];
            nlv[c] = nloc_ws[((size_t)(s * NT + ct)) * DK + tid];
        }
        mvs[c] = mws[s * NT + ct];
        dcv[c] = decs_ws[s * NT + ct];
        scv[c] = scs_ws[s * NT + ct];
    }

    #pragma unroll
    for (int c = 0; c < CPB; ++c){
        const int ct = ct0 + c;
        const size_t rowbase = (size_t)s * T + (size_t)ct * BT;

        // ---- P0: loads, gates, stage k ----
        float4 kr4[4], vr[4], qf[4];
        #pragma unroll
        for (int i = 0; i < 4; ++i){
            int idx = i * 1024 + tid * 4;
            kr4[i] = *(const float4*)(kg + rowbase * DK + idx);
            vr[i]  = *(const float4*)(vg + rowbase * DV + idx);
        }
        {
            const float* qrow = qg + (rowbase + 16 * w + ln) * DK;
            qf[0] = *(const float4*)(qrow + q8);
            qf[1] = *(const float4*)(qrow + q8 + 4);
            qf[2] = *(const float4*)(qrow + 32 + q8);
            qf[3] = *(const float4*)(qrow + 32 + q8 + 4);
        }
        if (tid < 64){
            float b = logsig_log2e(fvs[c]);
            #pragma unroll
            for (int off = 1; off < 64; off <<= 1){
                float y = __shfl_up(b, off);
                if (tid >= off) b += y;
            }
            float a = ivs[c] * LOG2E_F - b;
            float p = a;
            #pragma unroll
            for (int off = 1; off < 64; off <<= 1){
                float y = __shfl_up(p, off);
                if (tid >= off) p = fmaxf(p, y);
            }
            float M = fmaxf(mvs[c], p);
            colterm[tid] = a;
            Mr[tid] = M;
            rowfac[tid] = SCALE * exp2f(mvs[c] - M);
            dncl[tid] = exp2f(-(b + M));
        }
        // stage k (natural, split, SWZ vectorized writes)
        #pragma unroll
        for (int i = 0; i < 4; ++i){
            int idx = i * 1024 + tid * 4;
            int r = idx >> 6, c0 = idx & 63;
            float kv[4] = {kr4[i].x, kr4[i].y, kr4[i].z, kr4[i].w};
            ushort4v kh4, kl4;
            #pragma unroll
            for (int j = 0; j < 4; ++j){
                ushort_t h, l;
                split_bf(kv[j], h, l); kh4[j] = h; kl4[j] = l;
            }
            *(ushort4v*)&bufA[SWZ(r, c0)] = kh4;
            *(ushort4v*)&bufB[SWZ(r, c0)] = kl4;
        }
        // convert q to split fragments now (qf dies; saves P1 peak regs)
        short8 ah0, al0, ah1, al1;
        {
            float a0t[8] = {qf[0].x, qf[0].y, qf[0].z, qf[0].w, qf[1].x, qf[1].y, qf[1].z, qf[1].w};
            float a1t[8] = {qf[2].x, qf[2].y, qf[2].z, qf[2].w, qf[3].x, qf[3].y, qf[3].z, qf[3].w};
            #pragma unroll
            for (int j = 0; j < 8; ++j){
                ushort_t h, l;
                split_bf(a0t[j], h, l); ah0[j] = (short)h; al0[j] = (short)l;
                split_bf(a1t[j], h, l); ah1[j] = (short)h; al1[j] = (short)l;
            }
        }
        // issue A load for the C_run update (consumed in P2; latency hides under P1)
        f32x4 Ar[4];
        if (c + 1 < CPB){
            const float* Ab = A_ws + ((size_t)(s * NT + ct)) * 4096;
            #pragma unroll
            for (int i = 0; i < 4; ++i)
                Ar[i] = *(const f32x4*)(Ab + i * 1024 + tid * 4);
        }
        __syncthreads();   // #1: k staged; gates visible

        // ---- P1: qn, v^T stage, S-MFMA, Z, rowsum ----
        const int mrow = 16 * w + ln;
        {
            float p = 0.f;
            #pragma unroll
            for (int j = 0; j < 8; ++j){
                float qv0 = bf2f((ushort_t)ah0[j]) + bf2f((ushort_t)al0[j]);
                float qv1 = bf2f((ushort_t)ah1[j]) + bf2f((ushort_t)al1[j]);
                p = fmaf(qv0, nsh[q8 + j], p);
                p = fmaf(qv1, nsh[32 + q8 + j], p);
            }
            p += __shfl_xor(p, 16);
            p += __shfl_xor(p, 32);
            if (quad == 0) qn[mrow] = p;
        }
        #pragma unroll
        for (int i = 0; i < 4; ++i){
            int idx = i * 1024 + tid * 4;
            int r = idx >> 6, c0 = idx & 63;
            float vv[4] = {vr[i].x, vr[i].y, vr[i].z, vr[i].w};
            #pragma unroll
            for (int j = 0; j < 4; ++j) bufV[SWZ(c0 + j, r)] = f2bf(vv[j]);
        }
        f32x4 sacc[4];
        #pragma unroll
        for (int t = 0; t < 4; ++t){
            sacc[t] = (f32x4){0.f, 0.f, 0.f, 0.f};
            short8 bh0 = *(const short8*)&bufA[SWZ(16 * t + ln, q8)];
            short8 bh1 = *(const short8*)&bufA[SWZ(16 * t + ln, 32 + q8)];
            short8 bl0 = *(const short8*)&bufB[SWZ(16 * t + ln, q8)];
            short8 bl1 = *(const short8*)&bufB[SWZ(16 * t + ln, 32 + q8)];
            sacc[t] = MFMA16(ah0, bh0, sacc[t]);
            sacc[t] = MFMA16(ah1, bh1, sacc[t]);
            sacc[t] = MFMA16(ah0, bl0, sacc[t]);
            sacc[t] = MFMA16(ah1, bl1, sacc[t]);
            sacc[t] = MFMA16(al0, bh0, sacc[t]);
            sacc[t] = MFMA16(al1, bh1, sacc[t]);
        }
        {
            float rsum[4] = {0.f, 0.f, 0.f, 0.f};
            float Mrv[4];
            #pragma unroll
            for (int reg = 0; reg < 4; ++reg) Mrv[reg] = Mr[16 * w + quad * 4 + reg];
            #pragma unroll
            for (int t = 0; t < 4; ++t){
                int cc = 16 * t + ln;
                float cterm = colterm[cc];
                #pragma unroll
                for (int reg = 0; reg < 4; ++reg){
                    int r = 16 * w + quad * 4 + reg;
                    float vS = (cc <= r) ? sacc[t][reg] * SCALE * exp2f(cterm - Mrv[reg]) : 0.f;
                    bufZ[ZSW(r, cc)] = f2bf(vS);
                    rsum[reg] += vS;
                }
            }
            #pragma unroll
            for (int off = 1; off < 16; off <<= 1){
                #pragma unroll
                for (int reg = 0; reg < 4; ++reg) rsum[reg] += __shfl_xor(rsum[reg], off);
            }
            if (ln == 0){
                #pragma unroll
                for (int reg = 0; reg < 4; ++reg) rowsum[16 * w + quad * 4 + reg] = rsum[reg];
            }
        }
        __syncthreads();   // #2: k reads done; v^T + Z staged

        // ---- P2: stage CURRENT C_run, then advance the scan ----
        #pragma unroll
        for (int i = 0; i < 4; ++i){
            int idx = i * 1024 + tid * 4;
            int vrow = idx >> 6, k0 = idx & 63;
            float cv[4] = {Crun[i][0], Crun[i][1], Crun[i][2], Crun[i][3]};
            ushort4v ch4, cl4;
            #pragma unroll
            for (int j = 0; j < 4; ++j){
                ushort_t h, l;
                split_bf(cv[j], h, l); ch4[j] = h; cl4[j] = l;
            }
            *(ushort4v*)&bufA[SWZ(vrow, k0)] = ch4;
            *(ushort4v*)&bufB[SWZ(vrow, k0)] = cl4;
        }
        if (c + 1 < CPB){
            #pragma unroll
            for (int i = 0; i < 4; ++i)
                Crun[i] = Crun[i] * dcv[c] + Ar[i] * scv[c];
            if (tid < 64) nsh[tid] = nsh[tid] * dcv[c] + nlv[c] * scv[c];
        }
        __syncthreads();   // #3: C staged (and nsh advanced for next chunk)

        // ---- P3: qC MFMA, denom, Sv MFMA, epilogue ----
        f32x4 acc[4];
        #pragma unroll
        for (int t = 0; t < 4; ++t){
            acc[t] = (f32x4){0.f, 0.f, 0.f, 0.f};
            short8 bh0 = *(const short8*)&bufA[SWZ(16 * t + ln, q8)];
            short8 bh1 = *(const short8*)&bufA[SWZ(16 * t + ln, 32 + q8)];
            short8 bl0 = *(const short8*)&bufB[SWZ(16 * t + ln, q8)];
            short8 bl1 = *(const short8*)&bufB[SWZ(16 * t + ln, 32 + q8)];
            acc[t] = MFMA16(ah0, bh0, acc[t]);
            acc[t] = MFMA16(ah1, bh1, acc[t]);
            acc[t] = MFMA16(ah0, bl0, acc[t]);
            acc[t] = MFMA16(ah1, bl1, acc[t]);
            acc[t] = MFMA16(al0, bh0, acc[t]);
            acc[t] = MFMA16(al1, bh1, acc[t]);
        }
        float rf[4], inv[4];
        #pragma unroll
        for (int reg = 0; reg < 4; ++reg){
            int r = 16 * w + quad * 4 + reg;
            rf[reg] = rowfac[r];
            float dn = fabsf(rf[reg] * qn[r] + rowsum[r]);
            inv[reg] = 1.f / fmaxf(dn, dncl[r]);
        }
        #pragma unroll
        for (int t = 0; t < 4; ++t){
            #pragma unroll
            for (int reg = 0; reg < 4; ++reg) acc[t][reg] *= rf[reg];
        }
        short8 az0 = *(const short8*)&bufZ[ZSW(mrow, q8)];
        short8 az1 = *(const short8*)&bufZ[ZSW(mrow, 32 + q8)];
        #pragma unroll
        for (int t = 0; t < 4; ++t){
            short8 bh0 = *(const short8*)&bufV[SWZ(16 * t + ln, q8)];
            short8 bh1 = *(const short8*)&bufV[SWZ(16 * t + ln, 32 + q8)];
            acc[t] = MFMA16(az0, bh0, acc[t]);
            acc[t] = MFMA16(az1, bh1, acc[t]);
        }
        #pragma unroll
        for (int t = 0; t < 4; ++t){
            int cc = 16 * t + ln;
            #pragma unroll
            for (int reg = 0; reg < 4; ++reg){
                int r = 16 * w + quad * 4 + reg;
                out[(rowbase + r) * DV + cc] = acc[t][reg] * inv[reg];
            }
        }
        if (c + 1 < CPB) __syncthreads();   // #4: slab reuse barrier
    }
}

// ---------------- Fallback: fused sequential fp32 (no workspace) ----------------
__global__ __launch_bounds__(256) void fused_kernel(
    const float* __restrict__ qg, const float* __restrict__ kg, const float* __restrict__ vg,
    const float* __restrict__ ig, const float* __restrict__ fg,
    float* __restrict__ out, int T, int NT)
{
    const int s = blockIdx.x;
    const int tid = threadIdx.x;
    const int lane = tid & 63;

    __shared__ float X[BT][DK + 1];
    __shared__ float Y[BT][DK + 1];
    __shared__ float Cb[DK][DV];
    __shared__ __hip_bfloat16 Zh[BT][BT];
    __shared__ float colterm[BT], Mr[BT], rowfac[BT], dncl[BT], gscale[BT];
    __shared__ float nsh[DK], qn[BT], rowsum[BT], denom[BT];
    __shared__ float sh_dec;

    const float* qseq = qg + (size_t)s * T * DK;
    const float* kseq = kg + (size_t)s * T * DK;
    const float* vseq = vg + (size_t)s * T * DV;
    const float* iseq = ig + (size_t)s * T;
    const float* fseq = fg + (size_t)s * T;

    for (int idx = tid; idx < DK * DV; idx += 256) Cb[idx >> 6][idx & 63] = 0.f;
    if (tid < 64) nsh[lane] = 0.f;
    float m = 0.f;
    __syncthreads();

    const int r0 = (tid >> 4) * 4;
    const int c0 = (tid & 15) * 4;
    const int v0 = c0;

    for (int t = 0; t < NT; ++t){
        const size_t rb = (size_t)t * BT;
        if (tid < 64){
            float b = logsig_log2e(fseq[rb + lane]);
            #pragma unroll
            for (int off = 1; off < 64; off <<= 1){
                float y = __shfl_up(b, off);
                if (lane >= off) b += y;
            }
            float f_last = __shfl(b, 63);
            float a = iseq[rb + lane] * LOG2E_F - b;
            float p = a;
            #pragma unroll
            for (int off = 1; off < 64; off <<= 1){
                float y = __shfl_up(p, off);
                if (lane >= off) p = fmaxf(p, y);
            }
            float M = fmaxf(m, p);
            colterm[lane] = a;
            Mr[lane] = M;
            rowfac[lane] = SCALE * exp2f(m - M);
            dncl[lane] = exp2f(-(b + M));
            float g = a + f_last;
            float gm = g;
            #pragma unroll
            for (int off = 32; off > 0; off >>= 1) gm = fmaxf(gm, __shfl_xor(gm, off));
            float m_next = fmaxf(f_last + m, gm);
            gscale[lane] = exp2f(g - m_next);
            if (tid == 0) sh_dec = exp2f(f_last + m - m_next);
            m = m_next;
        }
        #pragma unroll
        for (int base = 0; base < BT * DK; base += 1024){
            int idx = base + tid * 4;
            int r = idx >> 6, c = idx & 63;
            float4 a4 = *(const float4*)(qseq + rb * DK + idx);
            X[r][c] = a4.x; X[r][c+1] = a4.y; X[r][c+2] = a4.z; X[r][c+3] = a4.w;
            float4 b4 = *(const float4*)(kseq + rb * DK + idx);
            Y[r][c] = b4.x; Y[r][c+1] = b4.y; Y[r][c+2] = b4.z; Y[r][c+3] = b4.w;
        }
        __syncthreads();

        float sacc[4][4] = {};
        for (int x = 0; x < DK; ++x){
            float xr[4], yc[4];
            #pragma unroll
            for (int j = 0; j < 4; ++j) xr[j] = X[r0 + j][x];
            #pragma unroll
            for (int j = 0; j < 4; ++j) yc[j] = Y[c0 + j][x];
            #pragma unroll
            for (int j = 0; j < 4; ++j)
                #pragma unroll
                for (int jj = 0; jj < 4; ++jj)
                    sacc[j][jj] = fmaf(xr[j], yc[jj], sacc[j][jj]);
        }
        float rs[4];
        #pragma unroll
        for (int j = 0; j < 4; ++j){
            int r = r0 + j;
            float Mrv = Mr[r];
            float acc = 0.f;
            #pragma unroll
            for (int jj = 0; jj < 4; ++jj){
                int c = c0 + jj;
                float vS = (c <= r) ? sacc[j][jj] * SCALE * exp2f(colterm[c] - Mrv) : 0.f;
                Zh[r][c] = __float2bfloat16(vS);
                acc += vS;
            }
            rs[j] = acc;
        }
        #pragma unroll
        for (int off = 1; off < 16; off <<= 1){
            #pragma unroll
            for (int j = 0; j < 4; ++j) rs[j] += __shfl_xor(rs[j], off);
        }
        if ((tid & 15) == 0){
            #pragma unroll
            for (int j = 0; j < 4; ++j) rowsum[r0 + j] = rs[j];
        }
        float acc1[4][4] = {};
        for (int x = 0; x < DK; ++x){
            float xr[4], yv[4];
            #pragma unroll
            for (int j = 0; j < 4; ++j) xr[j] = X[r0 + j][x];
            #pragma unroll
            for (int j = 0; j < 4; ++j) yv[j] = Cb[x][v0 + j];
            #pragma unroll
            for (int j = 0; j < 4; ++j)
                #pragma unroll
                for (int jj = 0; jj < 4; ++jj)
                    acc1[j][jj] = fmaf(xr[j], yv[jj], acc1[j][jj]);
        }
        if (tid < 64){
            float acc = 0.f;
            for (int x = 0; x < DK; ++x) acc = fmaf(X[lane][x], nsh[x], acc);
            qn[lane] = acc;
        }
        __syncthreads();

        #pragma unroll
        for (int base = 0; base < BT * DV; base += 1024){
            int idx = base + tid * 4;
            int r = idx >> 6, c = idx & 63;
            float4 a4 = *(const float4*)(vseq + rb * DV + idx);
            X[r][c] = a4.x; X[r][c+1] = a4.y; X[r][c+2] = a4.z; X[r][c+3] = a4.w;
        }
        if (tid < 64){
            float dn = fabsf(rowfac[lane] * qn[lane] + rowsum[lane]);
            denom[lane] = fmaxf(dn, dncl[lane]);
        }
        __syncthreads();

        float acc2[4][4] = {};
        for (int c = 0; c < BT; ++c){
            float zr[4], xv[4];
            #pragma unroll
            for (int j = 0; j < 4; ++j) zr[j] = __bfloat162float(Zh[r0 + j][c]);
            #pragma unroll
            for (int j = 0; j < 4; ++j) xv[j] = X[c][v0 + j];
            #pragma unroll
            for (int j = 0; j < 4; ++j)
                #pragma unroll
                for (int jj = 0; jj < 4; ++jj)
                    acc2[j][jj] = fmaf(zr[j], xv[jj], acc2[j][jj]);
        }
        #pragma unroll
        for (int j = 0; j < 4; ++j){
            int r = r0 + j;
            float rf = rowfac[r];
            float inv = 1.f / denom[r];
            float4 h4;
            h4.x = (acc1[j][0] * rf + acc2[j][0]) * inv;
            h4.y = (acc1[j][1] * rf + acc2[j][1]) * inv;
            h4.z = (acc1[j][2] * rf + acc2[j][2]) * inv;
            h4.w = (acc1[j][3] * rf + acc2[j][3]) * inv;
            *(float4*)(out + ((size_t)s * T + rb + r) * DV + v0) = h4;
        }
        {
            float dec = sh_dec;
            float cr[4][4];
            #pragma unroll
            for (int j = 0; j < 4; ++j)
                #pragma unroll
                for (int jj = 0; jj < 4; ++jj)
                    cr[j][jj] = Cb[r0 + j][c0 + jj] * dec;
            for (int c = 0; c < BT; ++c){
                float gs = gscale[c];
                float kd[4], xv[4];
                #pragma unroll
                for (int j = 0; j < 4; ++j) kd[j] = Y[c][r0 + j] * gs;
                #pragma unroll
                for (int jj = 0; jj < 4; ++jj) xv[jj] = X[c][c0 + jj];
                #pragma unroll
                for (int j = 0; j < 4; ++j)
                    #pragma unroll
                    for (int jj = 0; jj < 4; ++jj)
                        cr[j][jj] = fmaf(kd[j], xv[jj], cr[j][jj]);
            }
            #pragma unroll
            for (int j = 0; j < 4; ++j)
                #pragma unroll
                for (int jj = 0; jj < 4; ++jj)
                    Cb[r0 + j][c0 + jj] = cr[j][jj];
        }
        if (tid < 64){
            float acc = 0.f;
            for (int c = 0; c < BT; ++c) acc = fmaf(Y[c][lane], gscale[c], acc);
            nsh[lane] = nsh[lane] * sh_dec + acc;
        }
        __syncthreads();
    }
}

extern "C" void kernel_launch(void* const* d_in, const int* in_sizes, int n_in,
                              void* d_out, int out_size, void* d_ws, size_t ws_size,
                              hipStream_t stream)
{
    const float* q  = (const float*)d_in[0];
    const float* k  = (const float*)d_in[1];
    const float* v  = (const float*)d_in[2];
    const float* ii = (const float*)d_in[3];
    const float* ff = (const float*)d_in[4];
    float* out = (float*)d_out;

    const int T  = 4096;
    const int BH = in_sizes[3] / T;
    const int NT = T / BT;
    const int NG = NT / CPB;

    const size_t szA   = (size_t)BH * NT * DK * DV * sizeof(float);
    const size_t szCb  = (size_t)BH * NG * DK * DV * sizeof(float);
    const size_t szn   = (size_t)BH * NT * DK * sizeof(float);
    const size_t sznb  = (size_t)BH * NG * DK * sizeof(float);
    const size_t szs   = (size_t)BH * NT * sizeof(float);

    const size_t need_new = szA + szCb + szn + sznb + 5 * szs;

    if (ws_size >= need_new && NT == 64){
        char* p = (char*)d_ws;
        float* A_ws    = (float*)p;            p += szA;
        float* Cb_ws   = (float*)p;            p += szCb;
        float* nloc_ws = (float*)p;            p += szn;
        float* nb_ws   = (float*)p;            p += sznb;
        float* fl_ws   = (float*)p;            p += szs;
        float* mloc_ws = (float*)p;            p += szs;
        float* mws     = (float*)p;            p += szs;
        float* decs_ws = (float*)p;            p += szs;
        float* scs_ws  = (float*)p;
        stageA_kernel<<<dim3(NT, BH), 256, 0, stream>>>(k, v, ii, ff, A_ws, nloc_ws, fl_ws, mloc_ws, T, NT);
        stageB_kernel<<<dim3(16, BH), 256, 0, stream>>>(A_ws, nloc_ws, fl_ws, mloc_ws, Cb_ws, nb_ws, mws, decs_ws, scs_ws, NT);
        pass2_kernel<<<dim3(NG, BH), 256, 0, stream>>>(q, k, v, ii, ff, A_ws, Cb_ws, nb_ws, nloc_ws, mws, decs_ws, scs_ws, out, T, NT);
    } else {
        fused_kernel<<<dim3(BH), 256, 0, stream>>>(q, k, v, ii, ff, out, T, NT);
    }
}